// Round 2
// baseline (1564.797 us; speedup 1.0000x reference)
//
#include <hip/hip_runtime.h>
#include <hip/hip_bf16.h>
#include <stdint.h>

#define OUT_F 11008
#define IN_F  4096
#define M_TOK 8192   // 4 * 2048

typedef __attribute__((ext_vector_type(8))) __bf16 bf16x8;
typedef __attribute__((ext_vector_type(4))) float  f32x4;

__device__ __forceinline__ unsigned short f2bf(float f) {
    // round-to-nearest-even bf16 (inputs are finite)
    uint32_t u = __float_as_uint(f);
    u += 0x7FFFu + ((u >> 16) & 1u);
    return (unsigned short)(u >> 16);
}

// -------- dequant --------
// weight_packed delivered as int32 (harness promotes uint8 -> int32), one
// original packed byte (0..255) per int. weight_range/weight_min delivered
// as float32 (harness upcasts f16 -> f32).
// Each thread: 8 ints (32 B in) -> 16 bf16 weights (32 B out).
// Group = 512 weights = 256 packed bytes = 256 ints -> 32 threads/group.
__global__ __launch_bounds__(256) void dequant_w(
    const int*   __restrict__ packed,
    const float* __restrict__ wrange,
    const float* __restrict__ wmin,
    unsigned short* __restrict__ wb) {
    int idx = blockIdx.x * 256 + threadIdx.x;   // 0 .. 2818048
    const uint4* src = (const uint4*)(packed + (size_t)idx * 8);
    uint4 p0 = src[0];
    uint4 p1 = src[1];
    int g = idx >> 5;
    float r  = wrange[g] * (1.0f / 15.0f);
    float mn = wmin[g];
    uint32_t by[8] = {p0.x, p0.y, p0.z, p0.w, p1.x, p1.y, p1.z, p1.w};
    union { unsigned short s[16]; uint4 v[2]; } o;
    #pragma unroll
    for (int b = 0; b < 8; ++b) {
        uint32_t v = by[b] & 0xFFu;
        // low nibble -> even index, high nibble -> odd index
        o.s[2 * b]     = f2bf((float)(v & 15u) * r + mn);
        o.s[2 * b + 1] = f2bf((float)(v >> 4)  * r + mn);
    }
    uint4* dst = (uint4*)(wb + (size_t)idx * 16);
    dst[0] = o.v[0];
    dst[1] = o.v[1];
}

// -------- cast x fp32 -> bf16 --------
__global__ __launch_bounds__(256) void cvt_x(const float* __restrict__ x,
                                             unsigned short* __restrict__ xb) {
    size_t i = ((size_t)blockIdx.x * 256 + threadIdx.x) * 8;
    float4 a = *(const float4*)(x + i);
    float4 b = *(const float4*)(x + i + 4);
    union { unsigned short s[8]; uint4 v; } o;
    o.s[0] = f2bf(a.x); o.s[1] = f2bf(a.y); o.s[2] = f2bf(a.z); o.s[3] = f2bf(a.w);
    o.s[4] = f2bf(b.x); o.s[5] = f2bf(b.y); o.s[6] = f2bf(b.z); o.s[7] = f2bf(b.w);
    *(uint4*)(xb + i) = o.v;
}

// -------- async global->LDS, 16 B per lane --------
__device__ __forceinline__ void async16(const void* g, void* l) {
    __builtin_amdgcn_global_load_lds(
        (__attribute__((address_space(1))) unsigned int*)g,
        (__attribute__((address_space(3))) unsigned int*)l,
        16, 0, 0);
}

// -------- bf16 GEMM, B^T input: C[M,N] = A[M,K] * B[N,K]^T --------
// m97 structure: 128x128 block tile, BK=64, 256 threads (4 waves, 2x2),
// 4x4 16x16x32 fragments per wave, global_load_lds width-16 staging.
#define BM 128
#define BN 128
#define BK 64

__global__ __launch_bounds__(256) void gemm_bt(
    const unsigned short* __restrict__ A,   // [M,K] bf16 bits
    const unsigned short* __restrict__ B,   // [N,K] bf16 bits
    float* __restrict__ C,                  // [M,N] fp32
    int M, int N, int K) {
    __shared__ alignas(16) unsigned short As[BM * BK];  // 16 KiB
    __shared__ alignas(16) unsigned short Bs[BN * BK];  // 16 KiB

    const int tid  = threadIdx.x;
    const int wave = tid >> 6;
    const int lane = tid & 63;
    const int wm = (wave >> 1) * 64;
    const int wn = (wave & 1) * 64;
    const int m0 = blockIdx.y * BM;
    const int n0 = blockIdx.x * BN;

    const int frow = lane & 15;
    const int quad = lane >> 4;

    f32x4 acc[4][4];
    #pragma unroll
    for (int i = 0; i < 4; ++i)
        #pragma unroll
        for (int j = 0; j < 4; ++j)
            acc[i][j] = (f32x4){0.f, 0.f, 0.f, 0.f};

    for (int k0 = 0; k0 < K; k0 += BK) {
        #pragma unroll
        for (int r = 0; r < 4; ++r) {
            int chunk = r * 256 + tid;       // lane-contiguous LDS dest
            int row = chunk >> 3;
            int col = chunk & 7;
            async16(A + (size_t)(m0 + row) * K + k0 + col * 8, &As[chunk * 8]);
        }
        #pragma unroll
        for (int r = 0; r < 4; ++r) {
            int chunk = r * 256 + tid;
            int row = chunk >> 3;
            int col = chunk & 7;
            async16(B + (size_t)(n0 + row) * K + k0 + col * 8, &Bs[chunk * 8]);
        }
        __syncthreads();

        #pragma unroll
        for (int ks = 0; ks < BK; ks += 32) {
            bf16x8 af[4], bfr[4];
            #pragma unroll
            for (int i = 0; i < 4; ++i)
                af[i] = *(const bf16x8*)&As[(wm + i * 16 + frow) * BK + ks + quad * 8];
            #pragma unroll
            for (int j = 0; j < 4; ++j)
                bfr[j] = *(const bf16x8*)&Bs[(wn + j * 16 + frow) * BK + ks + quad * 8];
            #pragma unroll
            for (int i = 0; i < 4; ++i)
                #pragma unroll
                for (int j = 0; j < 4; ++j)
                    acc[i][j] = __builtin_amdgcn_mfma_f32_16x16x32_bf16(
                        af[i], bfr[j], acc[i][j], 0, 0, 0);
        }
        __syncthreads();
    }

    // C/D layout: col = lane&15, row = quad*4 + reg
    #pragma unroll
    for (int i = 0; i < 4; ++i) {
        #pragma unroll
        for (int j = 0; j < 4; ++j) {
            int n = n0 + wn + j * 16 + frow;
            #pragma unroll
            for (int r = 0; r < 4; ++r) {
                int m = m0 + wm + i * 16 + quad * 4 + r;
                C[(size_t)m * N + n] = acc[i][j][r];
            }
        }
    }
}

extern "C" void kernel_launch(void* const* d_in, const int* in_sizes, int n_in,
                              void* d_out, int out_size, void* d_ws, size_t ws_size,
                              hipStream_t stream) {
    const float* x      = (const float*)d_in[0];
    const int*   packed = (const int*)d_in[1];     // uint8 promoted to int32
    const float* wr     = (const float*)d_in[2];   // f16 upcast to f32
    const float* wmn    = (const float*)d_in[3];   // f16 upcast to f32
    float* out = (float*)d_out;

    // workspace: xb [8192*4096] bf16 (64 MiB), wb [11008*4096] bf16 (86 MiB)
    unsigned short* xb = (unsigned short*)d_ws;
    unsigned short* wb = (unsigned short*)((char*)d_ws + (size_t)M_TOK * IN_F * 2);

    cvt_x<<<(M_TOK * IN_F) / (256 * 8), 256, 0, stream>>>(x, xb);
    // 22544384 ints / 8 per thread / 256 per block = 11008 blocks
    dequant_w<<<(OUT_F * IN_F / 2) / (256 * 8), 256, 0, stream>>>(packed, wr, wmn, wb);

    dim3 grid(OUT_F / BN, M_TOK / BM);   // 86 x 64
    gemm_bt<<<grid, 256, 0, stream>>>(xb, wb, out, M_TOK, OUT_F, IN_F);
}